// Round 1
// baseline (4620.421 us; speedup 1.0000x reference)
//
#include <hip/hip_runtime.h>
#include <math.h>

#define N_NODES 50000
#define N_EDGES 600000
#define DIM 128
#define HEADS 8
#define DHEAD 16
// SCALE = sqrt(16) = 4 -> multiply by 0.25f

__device__ __forceinline__ int fenc(float f) {
    int i = __float_as_int(f);
    return (i >= 0) ? i : (i ^ 0x7fffffff);
}
__device__ __forceinline__ float fdec(int i) {
    return __int_as_float((i >= 0) ? i : (i ^ 0x7fffffff));
}

// ---------------- init ----------------
__global__ __launch_bounds__(256) void init_kernel(int* __restrict__ nmax,
                                                   float* __restrict__ ssum,
                                                   float* __restrict__ acc) {
    int i = blockIdx.x * 256 + threadIdx.x;
    if (i < N_NODES) nmax[i] = (int)0x807FFFFF;  // fenc(-inf)
    if (i < N_NODES * HEADS) ssum[i] = 0.0f;
    if (i < N_NODES * DIM) acc[i] = 0.0f;
}

// ---------------- GEMM: C[M x 128] = A[M x 128] @ B[128 x 128] + bias ----------------
// NORM: divide A[n,k] by (ssum[n*8 + k/16] + 1e-8) on load (fused softmax normalize)
#define BM 64
#define BK 32
template <bool NORM>
__global__ __launch_bounds__(256) void gemm128(const float* __restrict__ A,
                                               const float* __restrict__ B,
                                               const float* __restrict__ bias,
                                               const float* __restrict__ ssum,
                                               float* __restrict__ C, int M) {
    __shared__ float As[BM][BK + 4];    // stride 36
    __shared__ float Bs[BK][128 + 4];   // stride 132
    int tid = threadIdx.x;
    int tx = tid & 15, ty = tid >> 4;
    int r0 = blockIdx.x * BM;

    float accr[4][8];
#pragma unroll
    for (int i = 0; i < 4; i++)
#pragma unroll
        for (int j = 0; j < 8; j++) accr[i][j] = 0.0f;

    for (int kt = 0; kt < 128; kt += BK) {
        // A tile: 64x32, 512 float4, 2 per thread
#pragma unroll
        for (int l = 0; l < 2; l++) {
            int idx = tid + l * 256;
            int row = idx >> 3;
            int c4 = idx & 7;
            int gr = r0 + row;
            float4 a4 = make_float4(0.f, 0.f, 0.f, 0.f);
            if (gr < M) {
                a4 = *(const float4*)(A + gr * 128 + kt + c4 * 4);
                if (NORM) {
                    int head = (kt + c4 * 4) >> 4;
                    float inv = 1.0f / (ssum[gr * 8 + head] + 1e-8f);
                    a4.x *= inv; a4.y *= inv; a4.z *= inv; a4.w *= inv;
                }
            }
            *(float4*)(&As[row][c4 * 4]) = a4;
        }
        // B tile: 32x128, 1024 float4, 4 per thread
#pragma unroll
        for (int l = 0; l < 4; l++) {
            int idx = tid + l * 256;
            int row = idx >> 5;
            int c4 = idx & 31;
            float4 b4 = *(const float4*)(B + (kt + row) * 128 + c4 * 4);
            *(float4*)(&Bs[row][c4 * 4]) = b4;
        }
        __syncthreads();
#pragma unroll
        for (int kk = 0; kk < BK; kk++) {
            float a[4];
#pragma unroll
            for (int i = 0; i < 4; i++) a[i] = As[ty * 4 + i][kk];
            float4 b0 = *(float4*)(&Bs[kk][tx * 8]);
            float4 b1 = *(float4*)(&Bs[kk][tx * 8 + 4]);
            float b[8] = {b0.x, b0.y, b0.z, b0.w, b1.x, b1.y, b1.z, b1.w};
#pragma unroll
            for (int i = 0; i < 4; i++)
#pragma unroll
                for (int j = 0; j < 8; j++) accr[i][j] += a[i] * b[j];
        }
        __syncthreads();
    }
#pragma unroll
    for (int i = 0; i < 4; i++) {
        int gr = r0 + ty * 4 + i;
        if (gr >= M) continue;
#pragma unroll
        for (int j = 0; j < 8; j += 4) {
            float4 o;
            o.x = accr[i][j + 0] + bias[tx * 8 + j + 0];
            o.y = accr[i][j + 1] + bias[tx * 8 + j + 1];
            o.z = accr[i][j + 2] + bias[tx * 8 + j + 2];
            o.w = accr[i][j + 3] + bias[tx * 8 + j + 3];
            *(float4*)(C + gr * 128 + tx * 8 + j) = o;
        }
    }
}

// ---------------- edge pass 1: scores + node max ----------------
// thread = (edge, head); 8 consecutive lanes share an edge
__global__ __launch_bounds__(256) void edge_scores(const float* __restrict__ Q,
                                                   const float* __restrict__ K,
                                                   const int* __restrict__ rowi,
                                                   const int* __restrict__ coli,
                                                   const float* __restrict__ eattr,
                                                   float* __restrict__ scores,
                                                   int* __restrict__ nmax) {
    int tid = blockIdx.x * 256 + threadIdx.x;
    int e = tid >> 3;
    int h = tid & 7;
    if (e >= N_EDGES) return;
    int r = rowi[e], c = coli[e];
    const float4* q = (const float4*)(Q + r * 128 + h * 16);
    const float4* k = (const float4*)(K + c * 128 + h * 16);
    float dot = 0.0f;
#pragma unroll
    for (int i = 0; i < 4; i++) {
        float4 a = q[i], b = k[i];
        dot += a.x * b.x + a.y * b.y + a.z * b.z + a.w * b.w;
    }
    float s = dot * 0.25f + eattr[e];
    scores[tid] = s;
    float m = s;
    m = fmaxf(m, __shfl_xor(m, 1));
    m = fmaxf(m, __shfl_xor(m, 2));
    m = fmaxf(m, __shfl_xor(m, 4));
    if (h == 0) atomicMax(nmax + r, fenc(m));
}

// ---------------- edge pass 2: exp + segment sums (unnormalized) ----------------
__global__ __launch_bounds__(256) void edge_accum(const float* __restrict__ V,
                                                  const int* __restrict__ rowi,
                                                  const int* __restrict__ coli,
                                                  const float* __restrict__ scores,
                                                  const int* __restrict__ nmax,
                                                  float* __restrict__ ssum,
                                                  float* __restrict__ acc) {
    int tid = blockIdx.x * 256 + threadIdx.x;
    int e = tid >> 3;
    int h = tid & 7;
    if (e >= N_EDGES) return;
    int r = rowi[e], c = coli[e];
    float m = fdec(nmax[r]);
    float ex = __expf(scores[tid] - m);
    atomicAdd(ssum + r * 8 + h, ex);
    const float4* v = (const float4*)(V + c * 128 + h * 16);
    float* a = acc + r * 128 + h * 16;
#pragma unroll
    for (int i = 0; i < 4; i++) {
        float4 vv = v[i];
        atomicAdd(a + i * 4 + 0, ex * vv.x);
        atomicAdd(a + i * 4 + 1, ex * vv.y);
        atomicAdd(a + i * 4 + 2, ex * vv.z);
        atomicAdd(a + i * 4 + 3, ex * vv.w);
    }
}

extern "C" void kernel_launch(void* const* d_in, const int* in_sizes, int n_in,
                              void* d_out, int out_size, void* d_ws, size_t ws_size,
                              hipStream_t stream) {
    const float* x = (const float*)d_in[0];
    const int* ei = (const int*)d_in[1];   // [2, E] int32
    const float* eattr = (const float*)d_in[2];
    const float* Wq = (const float*)d_in[3];
    const float* bq = (const float*)d_in[4];
    const float* Wk = (const float*)d_in[5];
    const float* bk = (const float*)d_in[6];
    const float* Wv = (const float*)d_in[7];
    const float* bv = (const float*)d_in[8];
    const float* Wo = (const float*)d_in[9];
    const float* bo = (const float*)d_in[10];
    float* out = (float*)d_out;

    const int* rowi = ei;
    const int* coli = ei + N_EDGES;

    // workspace carve
    float* Q = (float*)d_ws;
    float* K = Q + (size_t)N_NODES * DIM;
    float* V = K + (size_t)N_NODES * DIM;
    float* scores = V + (size_t)N_NODES * DIM;            // E*H
    int* nmax = (int*)(scores + (size_t)N_EDGES * HEADS); // N
    float* ssum = (float*)(nmax + N_NODES);               // N*H
    float* acc = ssum + (size_t)N_NODES * HEADS;          // N*D

    // 1. init
    init_kernel<<<(N_NODES * DIM + 255) / 256, 256, 0, stream>>>(nmax, ssum, acc);

    // 2. Q/K/V projections
    int gblocks = (N_NODES + BM - 1) / BM;
    gemm128<false><<<gblocks, 256, 0, stream>>>(x, Wq, bq, nullptr, Q, N_NODES);
    gemm128<false><<<gblocks, 256, 0, stream>>>(x, Wk, bk, nullptr, K, N_NODES);
    gemm128<false><<<gblocks, 256, 0, stream>>>(x, Wv, bv, nullptr, V, N_NODES);

    // 3. edge scores + node max
    int eblocks = (N_EDGES * HEADS + 255) / 256;
    edge_scores<<<eblocks, 256, 0, stream>>>(Q, K, rowi, coli, eattr, scores, nmax);

    // 4. exp + segment sums
    edge_accum<<<eblocks, 256, 0, stream>>>(V, rowi, coli, scores, nmax, ssum, acc);

    // 5. output projection with fused normalization
    gemm128<true><<<gblocks, 256, 0, stream>>>(acc, Wo, bo, ssum, out, N_NODES);
}

// Round 2
// 515.711 us; speedup vs baseline: 8.9593x; 8.9593x over previous
//
#include <hip/hip_runtime.h>
#include <math.h>

#define N_NODES 50000
#define N_EDGES 600000
#define DIM 128
#define HEADS 8
#define DHEAD 16
// SCALE = sqrt(16) = 4 -> multiply by 0.25f

// ---------------- init: zero degree counts ----------------
__global__ __launch_bounds__(256) void init_counts(int* __restrict__ counts) {
    int i = blockIdx.x * 256 + threadIdx.x;
    if (i < N_NODES) counts[i] = 0;
}

// ---------------- histogram of destinations ----------------
__global__ __launch_bounds__(256) void hist_kernel(const int* __restrict__ rowi,
                                                   int* __restrict__ counts) {
    int e = blockIdx.x * 256 + threadIdx.x;
    if (e >= N_EDGES) return;
    atomicAdd(counts + rowi[e], 1);
}

// ---------------- exclusive scan over 50000 counts (single workgroup) ----------------
#define SCAN_T 1024
__global__ __launch_bounds__(SCAN_T) void scan_kernel(const int* __restrict__ counts,
                                                      int* __restrict__ start,
                                                      int* __restrict__ writeptr) {
    __shared__ int part[SCAN_T];
    int t = threadIdx.x;
    const int CH = (N_NODES + SCAN_T - 1) / SCAN_T;  // 49
    int base = t * CH;
    int sum = 0;
    for (int i = 0; i < CH; i++) {
        int idx = base + i;
        if (idx < N_NODES) sum += counts[idx];
    }
    part[t] = sum;
    __syncthreads();
    // Hillis-Steele inclusive scan of partials
    for (int off = 1; off < SCAN_T; off <<= 1) {
        int v = part[t];
        int add = (t >= off) ? part[t - off] : 0;
        __syncthreads();
        part[t] = v + add;
        __syncthreads();
    }
    int run = (t == 0) ? 0 : part[t - 1];
    for (int i = 0; i < CH; i++) {
        int idx = base + i;
        if (idx < N_NODES) {
            start[idx] = run;
            writeptr[idx] = run;
            run += counts[idx];
        }
    }
}

// ---------------- scatter edges into CSR buckets ----------------
__global__ __launch_bounds__(256) void scatter_kernel(const int* __restrict__ rowi,
                                                      const int* __restrict__ coli,
                                                      const float* __restrict__ eattr,
                                                      int* __restrict__ writeptr,
                                                      int* __restrict__ col_sorted,
                                                      float* __restrict__ ea_sorted) {
    int e = blockIdx.x * 256 + threadIdx.x;
    if (e >= N_EDGES) return;
    int r = rowi[e];
    int pos = atomicAdd(writeptr + r, 1);
    col_sorted[pos] = coli[e];
    ea_sorted[pos] = eattr[e];
}

// ---------------- fused attention: gather + online softmax + V accumulate ----------------
// thread = (node, head); 8 consecutive lanes = one node's 8 heads
__global__ __launch_bounds__(256) void fused_attn(const float* __restrict__ Q,
                                                  const float* __restrict__ K,
                                                  const float* __restrict__ V,
                                                  const int* __restrict__ start,
                                                  const int* __restrict__ counts,
                                                  const int* __restrict__ col_sorted,
                                                  const float* __restrict__ ea_sorted,
                                                  float* __restrict__ Aout) {
    int t = blockIdx.x * 256 + threadIdx.x;
    int n = t >> 3;
    int h = t & 7;
    if (n >= N_NODES) return;

    // load this (node, head)'s query slice: 16 floats
    float4 q0 = *(const float4*)(Q + n * 128 + h * 16 + 0);
    float4 q1 = *(const float4*)(Q + n * 128 + h * 16 + 4);
    float4 q2 = *(const float4*)(Q + n * 128 + h * 16 + 8);
    float4 q3 = *(const float4*)(Q + n * 128 + h * 16 + 12);

    int s0 = start[n];
    int s1 = s0 + counts[n];

    float m = -INFINITY;
    float l = 0.0f;
    float a0x = 0, a0y = 0, a0z = 0, a0w = 0;
    float a1x = 0, a1y = 0, a1z = 0, a1w = 0;
    float a2x = 0, a2y = 0, a2z = 0, a2w = 0;
    float a3x = 0, a3y = 0, a3z = 0, a3w = 0;

    for (int i = s0; i < s1; i++) {
        int c = col_sorted[i];
        float ea = ea_sorted[i];
        const float4* kp = (const float4*)(K + c * 128 + h * 16);
        float4 k0 = kp[0], k1 = kp[1], k2 = kp[2], k3 = kp[3];
        float dot = q0.x * k0.x + q0.y * k0.y + q0.z * k0.z + q0.w * k0.w
                  + q1.x * k1.x + q1.y * k1.y + q1.z * k1.z + q1.w * k1.w
                  + q2.x * k2.x + q2.y * k2.y + q2.z * k2.z + q2.w * k2.w
                  + q3.x * k3.x + q3.y * k3.y + q3.z * k3.z + q3.w * k3.w;
        float s = dot * 0.25f + ea;
        // max over the 8 heads of this node (8-lane group, 8 | 64)
        float em = s;
        em = fmaxf(em, __shfl_xor(em, 1));
        em = fmaxf(em, __shfl_xor(em, 2));
        em = fmaxf(em, __shfl_xor(em, 4));
        float nm = fmaxf(m, em);
        float scale = __expf(m - nm);   // first iter: exp(-inf) = 0
        float ex = __expf(s - nm);
        l = l * scale + ex;
        const float4* vp = (const float4*)(V + c * 128 + h * 16);
        float4 v0 = vp[0], v1 = vp[1], v2 = vp[2], v3 = vp[3];
        a0x = a0x * scale + ex * v0.x; a0y = a0y * scale + ex * v0.y;
        a0z = a0z * scale + ex * v0.z; a0w = a0w * scale + ex * v0.w;
        a1x = a1x * scale + ex * v1.x; a1y = a1y * scale + ex * v1.y;
        a1z = a1z * scale + ex * v1.z; a1w = a1w * scale + ex * v1.w;
        a2x = a2x * scale + ex * v2.x; a2y = a2y * scale + ex * v2.y;
        a2z = a2z * scale + ex * v2.z; a2w = a2w * scale + ex * v2.w;
        a3x = a3x * scale + ex * v3.x; a3y = a3y * scale + ex * v3.y;
        a3z = a3z * scale + ex * v3.z; a3w = a3w * scale + ex * v3.w;
        m = nm;
    }
    float inv = 1.0f / (l + 1e-8f);
    float* o = Aout + n * 128 + h * 16;
    *(float4*)(o + 0) = make_float4(a0x * inv, a0y * inv, a0z * inv, a0w * inv);
    *(float4*)(o + 4) = make_float4(a1x * inv, a1y * inv, a1z * inv, a1w * inv);
    *(float4*)(o + 8) = make_float4(a2x * inv, a2y * inv, a2z * inv, a2w * inv);
    *(float4*)(o + 12) = make_float4(a3x * inv, a3y * inv, a3z * inv, a3w * inv);
}

// ---------------- GEMM: C[M x 128] = A[M x 128] @ B[128 x 128] + bias ----------------
#define BM 64
#define BK 32
__global__ __launch_bounds__(256) void gemm128(const float* __restrict__ A,
                                               const float* __restrict__ B,
                                               const float* __restrict__ bias,
                                               float* __restrict__ C, int M) {
    __shared__ float As[BM][BK + 4];
    __shared__ float Bs[BK][128 + 4];
    int tid = threadIdx.x;
    int tx = tid & 15, ty = tid >> 4;
    int r0 = blockIdx.x * BM;

    float accr[4][8];
#pragma unroll
    for (int i = 0; i < 4; i++)
#pragma unroll
        for (int j = 0; j < 8; j++) accr[i][j] = 0.0f;

    for (int kt = 0; kt < 128; kt += BK) {
#pragma unroll
        for (int l = 0; l < 2; l++) {
            int idx = tid + l * 256;
            int row = idx >> 3;
            int c4 = idx & 7;
            int gr = r0 + row;
            float4 a4 = make_float4(0.f, 0.f, 0.f, 0.f);
            if (gr < M) a4 = *(const float4*)(A + gr * 128 + kt + c4 * 4);
            *(float4*)(&As[row][c4 * 4]) = a4;
        }
#pragma unroll
        for (int l = 0; l < 4; l++) {
            int idx = tid + l * 256;
            int row = idx >> 5;
            int c4 = idx & 31;
            float4 b4 = *(const float4*)(B + (kt + row) * 128 + c4 * 4);
            *(float4*)(&Bs[row][c4 * 4]) = b4;
        }
        __syncthreads();
#pragma unroll
        for (int kk = 0; kk < BK; kk++) {
            float a[4];
#pragma unroll
            for (int i = 0; i < 4; i++) a[i] = As[ty * 4 + i][kk];
            float4 b0 = *(float4*)(&Bs[kk][tx * 8]);
            float4 b1 = *(float4*)(&Bs[kk][tx * 8 + 4]);
            float b[8] = {b0.x, b0.y, b0.z, b0.w, b1.x, b1.y, b1.z, b1.w};
#pragma unroll
            for (int i = 0; i < 4; i++)
#pragma unroll
                for (int j = 0; j < 8; j++) accr[i][j] += a[i] * b[j];
        }
        __syncthreads();
    }
#pragma unroll
    for (int i = 0; i < 4; i++) {
        int gr = r0 + ty * 4 + i;
        if (gr >= M) continue;
#pragma unroll
        for (int j = 0; j < 8; j += 4) {
            float4 o;
            o.x = accr[i][j + 0] + bias[tx * 8 + j + 0];
            o.y = accr[i][j + 1] + bias[tx * 8 + j + 1];
            o.z = accr[i][j + 2] + bias[tx * 8 + j + 2];
            o.w = accr[i][j + 3] + bias[tx * 8 + j + 3];
            *(float4*)(C + gr * 128 + tx * 8 + j) = o;
        }
    }
}

extern "C" void kernel_launch(void* const* d_in, const int* in_sizes, int n_in,
                              void* d_out, int out_size, void* d_ws, size_t ws_size,
                              hipStream_t stream) {
    const float* x = (const float*)d_in[0];
    const int* ei = (const int*)d_in[1];   // [2, E] int32
    const float* eattr = (const float*)d_in[2];
    const float* Wq = (const float*)d_in[3];
    const float* bq = (const float*)d_in[4];
    const float* Wk = (const float*)d_in[5];
    const float* bk = (const float*)d_in[6];
    const float* Wv = (const float*)d_in[7];
    const float* bv = (const float*)d_in[8];
    const float* Wo = (const float*)d_in[9];
    const float* bo = (const float*)d_in[10];
    float* out = (float*)d_out;

    const int* rowi = ei;
    const int* coli = ei + N_EDGES;

    // workspace carve
    float* Q = (float*)d_ws;
    float* K = Q + (size_t)N_NODES * DIM;
    float* V = K + (size_t)N_NODES * DIM;
    float* Aout = V + (size_t)N_NODES * DIM;
    int* counts = (int*)(Aout + (size_t)N_NODES * DIM);
    int* start = counts + N_NODES;
    int* writeptr = start + N_NODES;
    int* col_sorted = writeptr + N_NODES;
    float* ea_sorted = (float*)(col_sorted + N_EDGES);

    int eblocks = (N_EDGES + 255) / 256;
    int nblocks = (N_NODES + 255) / 256;

    // CSR build
    init_counts<<<nblocks, 256, 0, stream>>>(counts);
    hist_kernel<<<eblocks, 256, 0, stream>>>(rowi, counts);
    scan_kernel<<<1, SCAN_T, 0, stream>>>(counts, start, writeptr);
    scatter_kernel<<<eblocks, 256, 0, stream>>>(rowi, coli, eattr, writeptr,
                                                col_sorted, ea_sorted);

    // Q/K/V projections
    int gblocks = (N_NODES + BM - 1) / BM;
    gemm128<<<gblocks, 256, 0, stream>>>(x, Wq, bq, Q, N_NODES);
    gemm128<<<gblocks, 256, 0, stream>>>(x, Wk, bk, K, N_NODES);
    gemm128<<<gblocks, 256, 0, stream>>>(x, Wv, bv, V, N_NODES);

    // fused gather-attention (no atomics)
    int ablocks = (N_NODES * HEADS + 255) / 256;
    fused_attn<<<ablocks, 256, 0, stream>>>(Q, K, V, start, counts,
                                            col_sorted, ea_sorted, Aout);

    // output projection
    gemm128<<<gblocks, 256, 0, stream>>>(Aout, Wo, bo, out, N_NODES);
}

// Round 3
// 313.762 us; speedup vs baseline: 14.7259x; 1.6436x over previous
//
#include <hip/hip_runtime.h>
#include <math.h>

#define N_NODES 50000
#define N_EDGES 600000
#define DIM 128
#define HEADS 8
#define DHEAD 16
#define NBLK 196  // (N_NODES+255)/256

typedef short v8s __attribute__((ext_vector_type(8)));
typedef float v16f __attribute__((ext_vector_type(16)));

__device__ __forceinline__ short f2bf(float f) {
    unsigned int u = __float_as_uint(f);
    unsigned int r = (u + 0x7fffu + ((u >> 16) & 1u)) >> 16;  // RNE
    return (short)r;
}

// ---------------- CSR build ----------------
__global__ __launch_bounds__(256) void init_counts(int* __restrict__ counts) {
    int i = blockIdx.x * 256 + threadIdx.x;
    if (i < N_NODES) counts[i] = 0;
}

__global__ __launch_bounds__(256) void hist_kernel(const int* __restrict__ rowi,
                                                   int* __restrict__ counts) {
    int e = blockIdx.x * 256 + threadIdx.x;
    if (e >= N_EDGES) return;
    atomicAdd(counts + rowi[e], 1);
}

__global__ __launch_bounds__(256) void reduce_partials(const int* __restrict__ counts,
                                                       int* __restrict__ partials) {
    int idx = blockIdx.x * 256 + threadIdx.x;
    int v = (idx < N_NODES) ? counts[idx] : 0;
#pragma unroll
    for (int off = 32; off > 0; off >>= 1) v += __shfl_down(v, off);
    __shared__ int ws4[4];
    if ((threadIdx.x & 63) == 0) ws4[threadIdx.x >> 6] = v;
    __syncthreads();
    if (threadIdx.x == 0) partials[blockIdx.x] = ws4[0] + ws4[1] + ws4[2] + ws4[3];
}

__global__ __launch_bounds__(256) void scan_partials(const int* __restrict__ partials,
                                                     int* __restrict__ offsets) {
    __shared__ int sh[256];
    int t = threadIdx.x;
    int v = (t < NBLK) ? partials[t] : 0;
    sh[t] = v;
    __syncthreads();
    for (int off = 1; off < 256; off <<= 1) {
        int a = sh[t];
        int b = (t >= off) ? sh[t - off] : 0;
        __syncthreads();
        sh[t] = a + b;
        __syncthreads();
    }
    if (t < NBLK) offsets[t] = sh[t] - v;  // exclusive
}

__global__ __launch_bounds__(256) void block_scan(const int* __restrict__ counts,
                                                  const int* __restrict__ offsets,
                                                  int* __restrict__ start,
                                                  int* __restrict__ writeptr) {
    __shared__ int sh[256];
    int t = threadIdx.x;
    int idx = blockIdx.x * 256 + t;
    int v = (idx < N_NODES) ? counts[idx] : 0;
    sh[t] = v;
    __syncthreads();
    for (int off = 1; off < 256; off <<= 1) {
        int a = sh[t];
        int b = (t >= off) ? sh[t - off] : 0;
        __syncthreads();
        sh[t] = a + b;
        __syncthreads();
    }
    if (idx < N_NODES) {
        int s = offsets[blockIdx.x] + sh[t] - v;
        start[idx] = s;
        writeptr[idx] = s;
    }
}

__global__ __launch_bounds__(256) void scatter_kernel(const int* __restrict__ rowi,
                                                      const int* __restrict__ coli,
                                                      const float* __restrict__ eattr,
                                                      int* __restrict__ writeptr,
                                                      int2* __restrict__ ep) {
    int e = blockIdx.x * 256 + threadIdx.x;
    if (e >= N_EDGES) return;
    int r = rowi[e];
    int pos = atomicAdd(writeptr + r, 1);
    ep[pos] = make_int2(coli[e], __float_as_int(eattr[e]));
}

// ---------------- conversions ----------------
__global__ __launch_bounds__(256) void convert_x(const float* __restrict__ x,
                                                 short* __restrict__ xb) {
    int base = (blockIdx.x * 256 + threadIdx.x) * 4;
    if (base >= N_NODES * DIM) return;
    float4 v = *(const float4*)(x + base);
    *(short4*)(xb + base) = make_short4(f2bf(v.x), f2bf(v.y), f2bf(v.z), f2bf(v.w));
}

__global__ __launch_bounds__(256) void convert_w(const float* __restrict__ Wq,
                                                 const float* __restrict__ Wk,
                                                 const float* __restrict__ Wv,
                                                 const float* __restrict__ Wo,
                                                 short* __restrict__ out) {
    int base = (blockIdx.x * 256 + threadIdx.x) * 4;
    if (base >= 4 * DIM * DIM) return;
    int seg = base >> 14;
    const float* src = (seg == 0) ? Wq : (seg == 1) ? Wk : (seg == 2) ? Wv : Wo;
    int off = base & (DIM * DIM - 1);
    float4 v = *(const float4*)(src + off);
    *(short4*)(out + base) = make_short4(f2bf(v.x), f2bf(v.y), f2bf(v.z), f2bf(v.w));
}

// ---------------- bf16 MFMA GEMM core: C[M x 128] = A[M x 128] @ W[128 x 128] + bias ----------------
// wave computes 32x32 tile via mfma_f32_32x32x16_bf16; block = 4 waves = 32 rows x 128 cols
__device__ __forceinline__ void gemm_core(const short* __restrict__ Ab,
                                          const short* __restrict__ Wb,
                                          const float* __restrict__ bias,
                                          float* __restrict__ C, int M) {
    int wave = threadIdx.x >> 6;
    int lane = threadIdx.x & 63;
    int col0 = wave * 32;
    int m32 = lane & 31;
    int quad = lane >> 5;  // 0 or 1

    v8s zeroS;
#pragma unroll
    for (int j = 0; j < 8; j++) zeroS[j] = 0;

    // preload B fragments: B[k][n], n = col0+m32, k = kt*16 + quad*8 + j
    v8s bf[8];
    const short* wp = Wb + col0 + m32;
#pragma unroll
    for (int kt = 0; kt < 8; kt++) {
        v8s f;
#pragma unroll
        for (int j = 0; j < 8; j++) f[j] = wp[(kt * 16 + quad * 8 + j) * 128];
        bf[kt] = f;
    }
    float bias_v = bias[col0 + m32];

    const int NT = (M + 31) / 32;
    for (int rt = blockIdx.x; rt < NT; rt += gridDim.x) {
        int row0 = rt * 32;
        int grow = row0 + m32;
        bool valid = grow < M;
        const v8s* ap = (const v8s*)(Ab + (size_t)grow * 128 + quad * 8);
        v16f acc;
#pragma unroll
        for (int r = 0; r < 16; r++) acc[r] = 0.0f;
#pragma unroll
        for (int kt = 0; kt < 8; kt++) {
            v8s af = zeroS;
            if (valid) af = ap[kt * 2];  // +16 shorts per kt
            acc = __builtin_amdgcn_mfma_f32_32x32x16_bf16(af, bf[kt], acc, 0, 0, 0);
        }
#pragma unroll
        for (int r = 0; r < 16; r++) {
            int row = (r & 3) + 8 * (r >> 2) + 4 * quad;
            int gr = row0 + row;
            if (gr < M) C[(size_t)gr * 128 + col0 + m32] = acc[r] + bias_v;
        }
    }
}

__global__ __launch_bounds__(256) void gemm_qkv(const short* __restrict__ xb,
                                                const short* __restrict__ Wb_all,
                                                const float* __restrict__ bq,
                                                const float* __restrict__ bk,
                                                const float* __restrict__ bv,
                                                float* __restrict__ Q,
                                                float* __restrict__ K,
                                                float* __restrict__ V) {
    int y = blockIdx.y;
    const short* Wb = Wb_all + y * DIM * DIM;
    const float* bias = (y == 0) ? bq : (y == 1) ? bk : bv;
    float* C = (y == 0) ? Q : (y == 1) ? K : V;
    gemm_core(xb, Wb, bias, C, N_NODES);
}

__global__ __launch_bounds__(256) void gemm_out(const short* __restrict__ Ab,
                                                const short* __restrict__ Wb_all,
                                                const float* __restrict__ bo,
                                                float* __restrict__ C) {
    gemm_core(Ab, Wb_all + 3 * DIM * DIM, bo, C, N_NODES);
}

// ---------------- fused attention: gather + online softmax + V accumulate ----------------
__global__ __launch_bounds__(256) void fused_attn(const float* __restrict__ Q,
                                                  const float* __restrict__ K,
                                                  const float* __restrict__ V,
                                                  const int* __restrict__ start,
                                                  const int* __restrict__ counts,
                                                  const int2* __restrict__ ep,
                                                  short* __restrict__ Aout) {
    int t = blockIdx.x * 256 + threadIdx.x;
    int n = t >> 3;
    int h = t & 7;
    if (n >= N_NODES) return;

    float4 q0 = *(const float4*)(Q + n * 128 + h * 16 + 0);
    float4 q1 = *(const float4*)(Q + n * 128 + h * 16 + 4);
    float4 q2 = *(const float4*)(Q + n * 128 + h * 16 + 8);
    float4 q3 = *(const float4*)(Q + n * 128 + h * 16 + 12);

    int s0 = start[n];
    int s1 = s0 + counts[n];

    float m = -INFINITY;
    float l = 0.0f;
    float a0x = 0, a0y = 0, a0z = 0, a0w = 0;
    float a1x = 0, a1y = 0, a1z = 0, a1w = 0;
    float a2x = 0, a2y = 0, a2z = 0, a2w = 0;
    float a3x = 0, a3y = 0, a3z = 0, a3w = 0;

    for (int i = s0; i < s1; i++) {
        int2 p = ep[i];
        int c = p.x;
        float ea = __int_as_float(p.y);
        const float4* kp = (const float4*)(K + c * 128 + h * 16);
        float4 k0 = kp[0], k1 = kp[1], k2 = kp[2], k3 = kp[3];
        float dot = q0.x * k0.x + q0.y * k0.y + q0.z * k0.z + q0.w * k0.w
                  + q1.x * k1.x + q1.y * k1.y + q1.z * k1.z + q1.w * k1.w
                  + q2.x * k2.x + q2.y * k2.y + q2.z * k2.z + q2.w * k2.w
                  + q3.x * k3.x + q3.y * k3.y + q3.z * k3.z + q3.w * k3.w;
        float s = dot * 0.25f + ea;
        float em = s;
        em = fmaxf(em, __shfl_xor(em, 1));
        em = fmaxf(em, __shfl_xor(em, 2));
        em = fmaxf(em, __shfl_xor(em, 4));
        float nm = fmaxf(m, em);
        float scale = __expf(m - nm);
        float ex = __expf(s - nm);
        l = l * scale + ex;
        const float4* vp = (const float4*)(V + c * 128 + h * 16);
        float4 v0 = vp[0], v1 = vp[1], v2 = vp[2], v3 = vp[3];
        a0x = a0x * scale + ex * v0.x; a0y = a0y * scale + ex * v0.y;
        a0z = a0z * scale + ex * v0.z; a0w = a0w * scale + ex * v0.w;
        a1x = a1x * scale + ex * v1.x; a1y = a1y * scale + ex * v1.y;
        a1z = a1z * scale + ex * v1.z; a1w = a1w * scale + ex * v1.w;
        a2x = a2x * scale + ex * v2.x; a2y = a2y * scale + ex * v2.y;
        a2z = a2z * scale + ex * v2.z; a2w = a2w * scale + ex * v2.w;
        a3x = a3x * scale + ex * v3.x; a3y = a3y * scale + ex * v3.y;
        a3z = a3z * scale + ex * v3.z; a3w = a3w * scale + ex * v3.w;
        m = nm;
    }
    float inv = 1.0f / (l + 1e-8f);
    unsigned short tmp[16];
    tmp[0] = f2bf(a0x * inv); tmp[1] = f2bf(a0y * inv);
    tmp[2] = f2bf(a0z * inv); tmp[3] = f2bf(a0w * inv);
    tmp[4] = f2bf(a1x * inv); tmp[5] = f2bf(a1y * inv);
    tmp[6] = f2bf(a1z * inv); tmp[7] = f2bf(a1w * inv);
    tmp[8] = f2bf(a2x * inv); tmp[9] = f2bf(a2y * inv);
    tmp[10] = f2bf(a2z * inv); tmp[11] = f2bf(a2w * inv);
    tmp[12] = f2bf(a3x * inv); tmp[13] = f2bf(a3y * inv);
    tmp[14] = f2bf(a3z * inv); tmp[15] = f2bf(a3w * inv);
    short* o = Aout + n * 128 + h * 16;
    *(v8s*)(o) = *(v8s*)tmp;
    *(v8s*)(o + 8) = *(v8s*)(tmp + 8);
}

extern "C" void kernel_launch(void* const* d_in, const int* in_sizes, int n_in,
                              void* d_out, int out_size, void* d_ws, size_t ws_size,
                              hipStream_t stream) {
    const float* x = (const float*)d_in[0];
    const int* ei = (const int*)d_in[1];
    const float* eattr = (const float*)d_in[2];
    const float* Wq = (const float*)d_in[3];
    const float* bq = (const float*)d_in[4];
    const float* Wk = (const float*)d_in[5];
    const float* bk = (const float*)d_in[6];
    const float* Wv = (const float*)d_in[7];
    const float* bv = (const float*)d_in[8];
    const float* Wo = (const float*)d_in[9];
    const float* bo = (const float*)d_in[10];
    float* out = (float*)d_out;

    const int* rowi = ei;
    const int* coli = ei + N_EDGES;

    // workspace carve
    float* Q = (float*)d_ws;
    float* K = Q + (size_t)N_NODES * DIM;
    float* V = K + (size_t)N_NODES * DIM;
    short* xb = (short*)(V + (size_t)N_NODES * DIM);
    short* Aout = xb + (size_t)N_NODES * DIM;
    short* Wb = Aout + (size_t)N_NODES * DIM;   // 4*128*128 shorts
    int* counts = (int*)(Wb + 4 * DIM * DIM);
    int* start = counts + N_NODES;
    int* writeptr = start + N_NODES;
    int* partials = writeptr + N_NODES;  // 256
    int* offsets = partials + 256;       // 256
    int2* ep = (int2*)(offsets + 256);   // E

    int eblocks = (N_EDGES + 255) / 256;

    // CSR build
    init_counts<<<NBLK, 256, 0, stream>>>(counts);
    hist_kernel<<<eblocks, 256, 0, stream>>>(rowi, counts);
    reduce_partials<<<NBLK, 256, 0, stream>>>(counts, partials);
    scan_partials<<<1, 256, 0, stream>>>(partials, offsets);
    block_scan<<<NBLK, 256, 0, stream>>>(counts, offsets, start, writeptr);
    scatter_kernel<<<eblocks, 256, 0, stream>>>(rowi, coli, eattr, writeptr, ep);

    // conversions
    convert_x<<<(N_NODES * DIM / 4 + 255) / 256, 256, 0, stream>>>(x, xb);
    convert_w<<<(4 * DIM * DIM / 4 + 255) / 256, 256, 0, stream>>>(Wq, Wk, Wv, Wo, Wb);

    // Q/K/V projections (bf16 MFMA)
    gemm_qkv<<<dim3(392, 3), 256, 0, stream>>>(xb, Wb, bq, bk, bv, Q, K, V);

    // fused gather-attention
    int ablocks = (N_NODES * HEADS + 255) / 256;
    fused_attn<<<ablocks, 256, 0, stream>>>(Q, K, V, start, counts, ep, Aout);

    // output projection (bf16 MFMA)
    gemm_out<<<392, 256, 0, stream>>>(Aout, Wb, bo, out);
}